// Round 2
// baseline (140.430 us; speedup 1.0000x reference)
//
#include <hip/hip_runtime.h>

// Problem constants (B=2, T=2048, D=1024, N_EXP=8, TOP_K=2, CAP_FACTOR=1.25)
#define N_TOK   4096
#define DDIM    1024
#define N_EXP   8
#define CAP     1280                       // floor(2*1.25*4096/8), even, >=4
#define CB_ELEMS (N_TOK * N_EXP * CAP)     // 41,943,040 floats per output tensor

#define ROUTER_BLOCKS 1024                 // 4 tokens/block (wave per token)
#define FILL_BLOCKS   4096
#define FILL_STRIDE   (FILL_BLOCKS * 256)  // float4 stride per iteration

typedef __attribute__((ext_vector_type(4))) float f32x4;

// ws layout: e0[4096] int | e1[4096] int | p0[4096] f32 | p1[4096] f32

// ---------------------------------------------------------------------------
// Kernel 1 (heterogeneous):
//   blocks [0, 1024):    router — 4096x8 GEMV, top-2, softmax over top-2
//   blocks [1024, 5120): zero-fill of cb_weight + sec_mask (335.5 MB, NT stores)
// Router blocks are dispatched first so their ~5 us hides under the fill.
// ---------------------------------------------------------------------------
__global__ __launch_bounds__(256) void router_fill_kernel(
    const float* __restrict__ x, const float* __restrict__ wg,
    int* __restrict__ e0, int* __restrict__ e1,
    float* __restrict__ p0, float* __restrict__ p1,
    float* __restrict__ out)
{
    if (blockIdx.x >= ROUTER_BLOCKS) {
        // -------- pure streaming zero-fill: no divisions, no compares --------
        const int bid = blockIdx.x - ROUTER_BLOCKS;           // 0..4095
        f32x4* dst = (f32x4*)(out + 8);                       // cb | mask, contiguous
        int i = bid * 256 + threadIdx.x;
        const f32x4 z = {0.f, 0.f, 0.f, 0.f};
#pragma unroll
        for (int it = 0; it < 20; ++it) {                     // 4096*256*20 = 20,971,520 float4
            __builtin_nontemporal_store(z, &dst[i]);
            i += FILL_STRIDE;
        }
        return;
    }

    // ------------------------------- router ---------------------------------
    const int wave = threadIdx.x >> 6;
    const int lane = threadIdx.x & 63;
    const int t = blockIdx.x * 4 + wave;

    const float4* xt  = (const float4*)(x + (size_t)t * DDIM);  // 256 float4
    const float4* wg4 = (const float4*)wg;                      // [8][256]

    float acc[N_EXP];
#pragma unroll
    for (int e = 0; e < N_EXP; ++e) acc[e] = 0.f;

#pragma unroll
    for (int it = 0; it < 4; ++it) {
        const int d4 = lane + it * 64;
        const float4 xv = xt[d4];
#pragma unroll
        for (int e = 0; e < N_EXP; ++e) {
            const float4 wv = wg4[e * 256 + d4];
            acc[e] = fmaf(xv.x, wv.x,
                     fmaf(xv.y, wv.y,
                     fmaf(xv.z, wv.z,
                     fmaf(xv.w, wv.w, acc[e]))));
        }
    }

#pragma unroll
    for (int e = 0; e < N_EXP; ++e) {
#pragma unroll
        for (int off = 32; off >= 1; off >>= 1)
            acc[e] += __shfl_xor(acc[e], off, 64);
    }

    if (lane == 0) {
        // stable top-2 (strict >) matches jax.lax.top_k tie-breaking
        float v0 = -3.402823466e38f, v1 = -3.402823466e38f;
        int   i0 = 0, i1 = 0;
#pragma unroll
        for (int e = 0; e < N_EXP; ++e) {
            const float v = acc[e];
            if (v > v0)      { v1 = v0; i1 = i0; v0 = v; i0 = e; }
            else if (v > v1) { v1 = v;  i1 = e; }
        }
        const float ex  = expf(v1 - v0);
        const float inv = 1.f / (1.f + ex);
        e0[t] = i0;
        e1[t] = i1;
        p0[t] = inv;        // softmax([v0,v1])[0]
        p1[t] = ex * inv;   // softmax([v0,v1])[1]
    }
}

// ---------------------------------------------------------------------------
// Kernel 2: ordered rank scan (k-major flattened order, matches ref cumsum)
// + used_capacity + scatter of the ~8192 nonzero (weight, mask) entries.
// One block, 16 waves; segment histogram -> exclusive prefix -> ballot ranks.
// ---------------------------------------------------------------------------
__global__ __launch_bounds__(1024) void scan_scatter_kernel(
    const int* __restrict__ e0, const int* __restrict__ e1,
    const float* __restrict__ p0, const float* __restrict__ p1,
    float* __restrict__ out)
{
    __shared__ int lds_e[2 * N_TOK];     // 32 KB: flattened expert ids
    __shared__ int seg_cnt[16][N_EXP];
    __shared__ int seg_base[16][N_EXP];

    for (int i = threadIdx.x; i < N_TOK; i += 1024) {
        lds_e[i]         = e0[i];
        lds_e[N_TOK + i] = e1[i];
    }
    __syncthreads();

    const int s    = threadIdx.x >> 6;      // segment = wave id, 512 entries each
    const int lane = threadIdx.x & 63;
    const unsigned long long lt = (1ull << lane) - 1ull;

    // Phase A: per-segment per-expert counts
    int cnt[N_EXP];
#pragma unroll
    for (int ex = 0; ex < N_EXP; ++ex) cnt[ex] = 0;
#pragma unroll
    for (int c = 0; c < 8; ++c) {
        const int e = lds_e[s * 512 + c * 64 + lane];
#pragma unroll
        for (int ex = 0; ex < N_EXP; ++ex)
            cnt[ex] += __popcll(__ballot(e == ex));
    }
    if (lane == 0) {
#pragma unroll
        for (int ex = 0; ex < N_EXP; ++ex) seg_cnt[s][ex] = cnt[ex];  // static idx
    }
    __syncthreads();

    // Phase B: exclusive prefix across segments (lane tid<8 owns expert tid)
    if (threadIdx.x < N_EXP) {
        int run = 0;
#pragma unroll
        for (int s2 = 0; s2 < 16; ++s2) {
            seg_base[s2][threadIdx.x] = run;
            run += seg_cnt[s2][threadIdx.x];
        }
        out[threadIdx.x] = (float)min(run, CAP);   // used_capacity
    }
    __syncthreads();

    // Phase C: exact sequential ranks via ballot prefix, then scatter
    int run[N_EXP];
#pragma unroll
    for (int ex = 0; ex < N_EXP; ++ex) run[ex] = seg_base[s][ex];

    float* cb   = out + 8;
    float* mask = out + 8 + (size_t)CB_ELEMS;

#pragma unroll
    for (int c = 0; c < 8; ++c) {
        const int i = s * 512 + c * 64 + lane;
        const int e = lds_e[i];
        int myrank = CAP;                       // default: no write
#pragma unroll
        for (int ex = 0; ex < N_EXP; ++ex) {
            const unsigned long long bal = __ballot(e == ex);
            if (e == ex) myrank = run[ex] + __popcll(bal & lt);
            run[ex] += __popcll(bal);
        }
        if (myrank < CAP) {                     // dropped tokens (rank>=cap) skipped
            const int   tok = (i < N_TOK) ? i : i - N_TOK;
            const float w   = (i < N_TOK) ? p0[tok] : p1[tok];
            const size_t off = (size_t)tok * (N_EXP * CAP) + (size_t)e * CAP + myrank;
            cb[off]   = w;
            mask[off] = (w != 0.f) ? 1.f : 0.f;
        }
    }
}

// ---------------------------------------------------------------------------
extern "C" void kernel_launch(void* const* d_in, const int* in_sizes, int n_in,
                              void* d_out, int out_size, void* d_ws, size_t ws_size,
                              hipStream_t stream)
{
    const float* x  = (const float*)d_in[0];   // [2,2048,1024] f32
    const float* wg = (const float*)d_in[1];   // [8,1024] f32
    float* out = (float*)d_out;                // [8] used | [41.94M] cb | [41.94M] mask

    char*  ws = (char*)d_ws;
    int*   e0 = (int*)(ws);
    int*   e1 = (int*)(ws + 16384);
    float* p0 = (float*)(ws + 32768);
    float* p1 = (float*)(ws + 49152);

    router_fill_kernel<<<ROUTER_BLOCKS + FILL_BLOCKS, 256, 0, stream>>>(
        x, wg, e0, e1, p0, p1, out);
    scan_scatter_kernel<<<1, 1024, 0, stream>>>(e0, e1, p0, p1, out);
}

// Round 3
// 82.630 us; speedup vs baseline: 1.6995x; 1.6995x over previous
//
#include <hip/hip_runtime.h>

// Problem constants (B=2, T=2048, D=1024, N_EXP=8, TOP_K=2, CAP_FACTOR=1.25)
#define N_TOK   4096
#define DDIM    1024
#define N_EXP   8
#define CAP     1280                       // floor(2*1.25*4096/8), even, >=4
#define ROW     (N_EXP * CAP)              // 10240 floats per token row
#define CB_ELEMS (N_TOK * ROW)             // 41,943,040 floats per output tensor

typedef __attribute__((ext_vector_type(4))) float f32x4;

// ws layout:
//   [0,     16384) : int  e0[4096]
//   [16384, 32768) : int  e1[4096]
//   [32768, 49152) : f32  p0[4096]
//   [49152, 65536) : f32  p1[4096]
//   [65536, 98304) : int2 r01[4096]  {(e0<<16|rank0), (e1<<16|rank1)}

// ---------------------------------------------------------------------------
// Kernel 1: router — 4096x8 GEMV, top-2, softmax over the 2 selected logits.
// One wave per token; lanes split D=1024 as float4 chunks. (proven in R1)
// ---------------------------------------------------------------------------
__global__ __launch_bounds__(256) void router_kernel(
    const float* __restrict__ x, const float* __restrict__ wg,
    int* __restrict__ e0, int* __restrict__ e1,
    float* __restrict__ p0, float* __restrict__ p1)
{
    const int wave = threadIdx.x >> 6;
    const int lane = threadIdx.x & 63;
    const int t = blockIdx.x * 4 + wave;

    const float4* xt  = (const float4*)(x + (size_t)t * DDIM);  // 256 float4
    const float4* wg4 = (const float4*)wg;                      // [8][256]

    float acc[N_EXP];
#pragma unroll
    for (int e = 0; e < N_EXP; ++e) acc[e] = 0.f;

#pragma unroll
    for (int it = 0; it < 4; ++it) {
        const int d4 = lane + it * 64;
        const float4 xv = xt[d4];
#pragma unroll
        for (int e = 0; e < N_EXP; ++e) {
            const float4 wv = wg4[e * 256 + d4];
            acc[e] = fmaf(xv.x, wv.x,
                     fmaf(xv.y, wv.y,
                     fmaf(xv.z, wv.z,
                     fmaf(xv.w, wv.w, acc[e]))));
        }
    }

#pragma unroll
    for (int e = 0; e < N_EXP; ++e) {
#pragma unroll
        for (int off = 32; off >= 1; off >>= 1)
            acc[e] += __shfl_xor(acc[e], off, 64);
    }

    if (lane == 0) {
        // stable top-2 (strict >) matches jax.lax.top_k tie-breaking
        float v0 = -3.402823466e38f, v1 = -3.402823466e38f;
        int   i0 = 0, i1 = 0;
#pragma unroll
        for (int e = 0; e < N_EXP; ++e) {
            const float v = acc[e];
            if (v > v0)      { v1 = v0; i1 = i0; v0 = v; i0 = e; }
            else if (v > v1) { v1 = v;  i1 = e; }
        }
        const float ex  = expf(v1 - v0);
        const float inv = 1.f / (1.f + ex);
        e0[t] = i0;
        e1[t] = i1;
        p0[t] = inv;        // softmax([v0,v1])[0]
        p1[t] = ex * inv;   // softmax([v0,v1])[1]
    }
}

// ---------------------------------------------------------------------------
// Kernel 2: ordered rank scan (k-major flattened order == ref cumsum order).
// 1 block, 16 waves: segment histogram -> exclusive prefix -> ballot ranks.
// Outputs packed (e<<16|rank) per (token, k) and used_capacity. No scatter.
// ---------------------------------------------------------------------------
__global__ __launch_bounds__(1024) void scan_kernel(
    const int* __restrict__ e0, const int* __restrict__ e1,
    int2* __restrict__ r01, float* __restrict__ out)
{
    __shared__ int lds_e[2 * N_TOK];     // 32 KB
    __shared__ int seg_cnt[16][N_EXP];
    __shared__ int seg_base[16][N_EXP];

    for (int i = threadIdx.x; i < N_TOK; i += 1024) {
        lds_e[i]         = e0[i];
        lds_e[N_TOK + i] = e1[i];
    }
    __syncthreads();

    const int s    = threadIdx.x >> 6;      // segment = wave id, 512 entries
    const int lane = threadIdx.x & 63;
    const unsigned long long lt = (1ull << lane) - 1ull;  // lane 63: 0x7FFF..

    // Phase A: per-segment per-expert counts
    int cnt[N_EXP];
#pragma unroll
    for (int ex = 0; ex < N_EXP; ++ex) cnt[ex] = 0;
#pragma unroll
    for (int c = 0; c < 8; ++c) {
        const int e = lds_e[s * 512 + c * 64 + lane];
#pragma unroll
        for (int ex = 0; ex < N_EXP; ++ex)
            cnt[ex] += __popcll(__ballot(e == ex));
    }
    if (lane == 0) {
#pragma unroll
        for (int ex = 0; ex < N_EXP; ++ex) seg_cnt[s][ex] = cnt[ex];
    }
    __syncthreads();

    // Phase B: exclusive prefix across segments; thread ex<8 owns expert ex
    if (threadIdx.x < N_EXP) {
        int run = 0;
#pragma unroll
        for (int s2 = 0; s2 < 16; ++s2) {
            seg_base[s2][threadIdx.x] = run;
            run += seg_cnt[s2][threadIdx.x];
        }
        out[threadIdx.x] = (float)min(run, CAP);   // used_capacity
    }
    __syncthreads();

    // Phase C: exact sequential ranks via ballot prefix; pack (e<<16|rank)
    int run[N_EXP];
#pragma unroll
    for (int ex = 0; ex < N_EXP; ++ex) run[ex] = seg_base[s][ex];

#pragma unroll
    for (int c = 0; c < 8; ++c) {
        const int i = s * 512 + c * 64 + lane;
        const int e = lds_e[i];
        int myrank = 0;
#pragma unroll
        for (int ex = 0; ex < N_EXP; ++ex) {
            const unsigned long long bal = __ballot(e == ex);
            if (e == ex) myrank = run[ex] + __popcll(bal & lt);
            run[ex] += __popcll(bal);
        }
        const int er = (e << 16) | myrank;          // myrank <= 8191, fits
        if (i < N_TOK) r01[i].x = er;
        else           r01[i - N_TOK].y = er;
    }
}

// ---------------------------------------------------------------------------
// Kernel 3: fill — one block per token. Stream zeros over the token's cb row
// (40 KB) + mask row (40 KB) with regular f32x4 stores (no div, no compares),
// then threads 0/1 overwrite the <=2 nonzero slots. __syncthreads() gives
// vmcnt(0)+barrier between the zero pass and the fixup -> ordered.
// ---------------------------------------------------------------------------
__global__ __launch_bounds__(256) void fill_kernel(
    const int2* __restrict__ r01, const float* __restrict__ p0,
    const float* __restrict__ p1, float* __restrict__ out)
{
    const int t = blockIdx.x;
    float* cb_row = out + 8 + (size_t)t * ROW;
    float* mk_row = cb_row + (size_t)CB_ELEMS;
    f32x4* cb4 = (f32x4*)cb_row;                 // 2560 f32x4
    f32x4* mk4 = (f32x4*)mk_row;
    const f32x4 z = {0.f, 0.f, 0.f, 0.f};

#pragma unroll
    for (int it = 0; it < 10; ++it) cb4[threadIdx.x + it * 256] = z;
#pragma unroll
    for (int it = 0; it < 10; ++it) mk4[threadIdx.x + it * 256] = z;

    __syncthreads();

    if (threadIdx.x < 2) {
        const int2  rr = r01[t];
        const int   er = threadIdx.x ? rr.y : rr.x;
        const float w  = threadIdx.x ? p1[t] : p0[t];
        const int   r  = er & 0xFFFF;
        const int   e  = er >> 16;
        if (r < CAP) {                           // dropped tokens skipped
            cb_row[e * CAP + r] = w;
            mk_row[e * CAP + r] = (w != 0.f) ? 1.f : 0.f;
        }
    }
}

// ---------------------------------------------------------------------------
extern "C" void kernel_launch(void* const* d_in, const int* in_sizes, int n_in,
                              void* d_out, int out_size, void* d_ws, size_t ws_size,
                              hipStream_t stream)
{
    const float* x  = (const float*)d_in[0];   // [2,2048,1024] f32
    const float* wg = (const float*)d_in[1];   // [8,1024] f32
    float* out = (float*)d_out;                // [8] used | cb | mask

    char*  ws  = (char*)d_ws;
    int*   e0  = (int*)(ws);
    int*   e1  = (int*)(ws + 16384);
    float* p0  = (float*)(ws + 32768);
    float* p1  = (float*)(ws + 49152);
    int2*  r01 = (int2*)(ws + 65536);

    router_kernel<<<N_TOK / 4, 256, 0, stream>>>(x, wg, e0, e1, p0, p1);
    scan_kernel<<<1, 1024, 0, stream>>>(e0, e1, r01, out);
    fill_kernel<<<N_TOK, 256, 0, stream>>>(r01, p0, p1, out);
}